// Round 3
// baseline (305.378 us; speedup 1.0000x reference)
//
#include <hip/hip_runtime.h>

#define CV_B 8
#define CV_C 128
#define CV_H 128
#define CV_W 240
#define CV_V 48
#define BSTRIDE 17      // band leading-dim pad (floats)

typedef __attribute__((ext_vector_type(8))) short bf16x8;
typedef __attribute__((ext_vector_type(4))) float f32x4;

// RTNE pack of two fp32 -> packed bf16x2
__device__ __forceinline__ unsigned int pack2_bf16(float f0, float f1) {
    unsigned int u0 = __float_as_uint(f0);
    unsigned int u1 = __float_as_uint(f1);
    u0 += 0x7fffu + ((u0 >> 16) & 1u);
    u1 += 0x7fffu + ((u1 >> 16) & 1u);
    return (u0 >> 16) | (u1 & 0xffff0000u);
}

__device__ __forceinline__ bf16x8 pack8(const float v[8]) {
    union { unsigned int u[4]; bf16x8 h; } cv;
    cv.u[0] = pack2_bf16(v[0], v[1]);
    cv.u[1] = pack2_bf16(v[2], v[3]);
    cv.u[2] = pack2_bf16(v[4], v[5]);
    cv.u[3] = pack2_bf16(v[6], v[7]);
    return cv.h;
}

// No __syncthreads anywhere: each wave is fully independent.
// Wave owns 2 adjacent 16-col x-tiles; loads MFMA fragments DIRECTLY from
// global (the lane->element map of a coalesced plane-strided load IS the
// A/B fragment layout, HW-verified in round 1). LDS only for the per-wave
// diagonal->row band transpose.
__global__ __launch_bounds__(256, 4) void cost_volume_kernel(
        const float* __restrict__ Lf, const float* __restrict__ Rf,
        float* __restrict__ out)
{
    __shared__ float band[4][2][CV_V * BSTRIDE];   // 4 waves x 2 tiles: 26.1 KB

    const int t    = threadIdx.x;
    const int wv   = t >> 6;
    const int lane = t & 63;
    const int n    = lane & 15;
    const int quad = lane >> 4;

    const int half = blockIdx.x;            // 0: tiles 0..7, 1: tiles 8..14
    const int y    = blockIdx.y;
    const int b    = blockIdx.z;

    const int T0 = half * 8 + wv * 2;       // first x-tile of this wave
    const int nt = (T0 + 1 < 15) ? 2 : 1;   // last wave of half 1 has 1 tile
    const int x0 = T0 * 16;

    const int plane = CV_H * CV_W;
    const float* Lrow = Lf + (b * CV_C) * plane + y * CV_W;
    const float* Rrow = Rf + (b * CV_C) * plane + y * CV_W;

    const int kbase = quad * 8;             // fragment k-offset for this lane

    // ---- A fragments: nt tiles x 4 K-chunks, straight from global ----
    bf16x8 aF[2][4];
#pragma unroll
    for (int e = 0; e < 2; ++e) {
        if (e < nt) {
            const float* p = Lrow + x0 + 16 * e + n;
#pragma unroll
            for (int ks = 0; ks < 4; ++ks) {
                float v[8];
#pragma unroll
                for (int jj = 0; jj < 8; ++jj)
                    v[jj] = p[(ks * 32 + kbase + jj) * plane];
                aF[e][ks] = pack8(v);
            }
        }
    }

    float* band0 = &band[wv][0][0];
    float* band1 = &band[wv][1][0];

    // ---- sweep j-tiles of the union window [T0-3, T0+nt-1] ----
    for (int w = T0 - 3; w <= T0 + nt - 1; ++w) {
        const int j0 = 16 * w;
        const int jg = j0 + n;              // this lane's right-image column
        const bool ok = (jg >= 0);
        const float* p = Rrow + jg;

        bf16x8 bF[4];
#pragma unroll
        for (int ks = 0; ks < 4; ++ks) {
            float v[8];
#pragma unroll
            for (int jj = 0; jj < 8; ++jj)
                v[jj] = ok ? p[(ks * 32 + kbase + jj) * plane] : 0.0f;
            bF[ks] = pack8(v);
        }

#pragma unroll
        for (int e = 0; e < 2; ++e) {
            if (e < nt && w >= T0 + e - 3 && w <= T0 + e) {
                f32x4 acc = {0.f, 0.f, 0.f, 0.f};
#pragma unroll
                for (int ks = 0; ks < 4; ++ks)
                    acc = __builtin_amdgcn_mfma_f32_16x16x32_bf16(aF[e][ks], bF[ks], acc, 0, 0, 0);
                // C: col=n -> j, row=quad*4+r -> x.  i = x - j
                float* bd = e ? band1 : band0;
                const int ibase = 16 * (T0 + e - w);
#pragma unroll
                for (int r = 0; r < 4; ++r) {
                    const int xloc = quad * 4 + r;
                    const int i    = ibase + xloc - n;
                    if (i >= 0 && i < CV_V)
                        bd[i * BSTRIDE + xloc] = acc[r] * (1.0f / 128.0f);
                }
            }
        }
    }

    // ---- store bands: 48 i-rows x 16 x, 64B segments, wave-local ----
#pragma unroll
    for (int e = 0; e < 2; ++e) {
        if (e < nt) {
            const float* bd = e ? band1 : band0;
            const int xb = x0 + 16 * e;
#pragma unroll
            for (int uu = 0; uu < 12; ++uu) {
                const int idx = lane + uu * 64;
                const int i   = idx >> 4;
                const int xx  = idx & 15;
                out[((b * CV_V + i) * CV_H + y) * CV_W + xb + xx] = bd[i * BSTRIDE + xx];
            }
        }
    }
}

extern "C" void kernel_launch(void* const* d_in, const int* in_sizes, int n_in,
                              void* d_out, int out_size, void* d_ws, size_t ws_size,
                              hipStream_t stream)
{
    const float* Lf = (const float*)d_in[0];
    const float* Rf = (const float*)d_in[1];
    float* o = (float*)d_out;
    dim3 grid(2, CV_H, CV_B);   // 2048 blocks x 256 thr = 8192 independent waves
    dim3 block(256);
    hipLaunchKernelGGL(cost_volume_kernel, grid, block, 0, stream, Lf, Rf, o);
}

// Round 4
// 287.494 us; speedup vs baseline: 1.0622x; 1.0622x over previous
//
#include <hip/hip_runtime.h>
#include <hip/hip_fp16.h>

#define CV_B 8
#define CV_C 128
#define CV_H 128
#define CV_W 240
#define CV_V 48
#define PLANE (CV_H * CV_W)
#define GUARD 48                 // zero guard (half2 words) left of each R row
#define ROWW (GUARD + CV_W)      // 288 half2 words per LDS row
#define NCP 16                   // c-pairs per chunk (= 32 channels)
#define NCHUNK 4                 // 4 chunks x 32 c = 128 c

// No MFMA: the c-reduction would force 64-B strided gathers (measured 2.65 TB/s
// wall). Instead: stream full 960-B rows, pack (c,c+1) half2 pairs, v_pk_fma_f16.
__global__ __launch_bounds__(256, 3) void cost_volume_kernel(
        const float* __restrict__ Lf, const float* __restrict__ Rf,
        float* __restrict__ out)
{
    // [side][c-pair][guard+240]: L = side 0, R = side 1 (guard zeros -> exact 0
    // for j<0, i.e. reference's where(col>=i, ., 0)).  36.9 KB.
    __shared__ __align__(16) __half2 sBuf[2][NCP][ROWW];

    const int t  = threadIdx.x;
    const int y  = blockIdx.x;
    const int b  = blockIdx.y;
    const int wv = t >> 6;          // wave id: compute i-group AND load role
    const int u  = t & 63;          // lane: x-group (x0 = 4u), u<60 active
    const bool act = (u < 60);

    const float* Lrow = Lf + (size_t)(b * CV_C) * PLANE + y * CV_W;
    const float* Rrow = Rf + (size_t)(b * CV_C) * PLANE + y * CV_W;

    // load roles: waves 0,1 stage L pairs 0..15; waves 2,3 stage R pairs 0..15
    const int side = wv >> 1;
    const int a0   = (wv & 1) * 8;
    const float* Srow = side ? Rrow : Lrow;

    // ---- zero guards once (data writes never touch words [0, GUARD)) ----
    for (int idx = t; idx < 2 * NCP * GUARD; idx += 256) {
        const int s  = idx / (NCP * GUARD);
        const int rm = idx % (NCP * GUARD);
        sBuf[s][rm / GUARD][rm % GUARD] = __floats2half2_rn(0.f, 0.f);
    }

    // ---- prologue: load + commit chunk 0 ----
    float4 f0[8], f1[8];
    if (act) {
#pragma unroll
        for (int q = 0; q < 8; ++q) {
            const float* p = Srow + (size_t)(2 * (a0 + q)) * PLANE + 4 * u;
            f0[q] = *(const float4*)p;            // row c   (960 B contiguous/inst)
            f1[q] = *(const float4*)(p + PLANE);  // row c+1
        }
#pragma unroll
        for (int q = 0; q < 8; ++q) {
            union { float4 v; __half2 h[4]; } wbuf;
            wbuf.h[0] = __floats2half2_rn(f0[q].x, f1[q].x);
            wbuf.h[1] = __floats2half2_rn(f0[q].y, f1[q].y);
            wbuf.h[2] = __floats2half2_rn(f0[q].z, f1[q].z);
            wbuf.h[3] = __floats2half2_rn(f0[q].w, f1[q].w);
            *(float4*)&sBuf[side][a0 + q][GUARD + 4 * u] = wbuf.v;
        }
    }
    __syncthreads();

    // ---- accumulators: thread tile = 4 x  X  12 i  (i = 12*wv + r) ----
    __half2 acc[4][12];
#pragma unroll
    for (int xx = 0; xx < 4; ++xx)
#pragma unroll
        for (int r = 0; r < 12; ++r) acc[xx][r] = __floats2half2_rn(0.f, 0.f);

    const int baseL = GUARD + 4 * u;            // 16-B aligned
    const int baseR = GUARD - 12 - 12 * wv + 4 * u;  // = 36+4u-12wv >= 0, %4==0

    for (int k = 0; k < NCHUNK; ++k) {
        // 1) issue next chunk's global loads early (in flight through compute)
        const bool pf = (k + 1 < NCHUNK);
        if (pf && act) {
#pragma unroll
            for (int q = 0; q < 8; ++q) {
                const float* p = Srow + (size_t)((k + 1) * 32 + 2 * (a0 + q)) * PLANE + 4 * u;
                f0[q] = *(const float4*)p;
                f1[q] = *(const float4*)(p + PLANE);
            }
        }

        // 2) compute chunk k from LDS
        if (act) {
#pragma unroll
            for (int cp = 0; cp < NCP; ++cp) {
                union { float4 v; __half2 h[4]; } lv, rw[4];
                lv.v = *(const float4*)&sBuf[0][cp][baseL];
#pragma unroll
                for (int kk = 0; kk < 4; ++kk)
                    rw[kk].v = *(const float4*)&sBuf[1][cp][baseR + 4 * kk];
#pragma unroll
                for (int r = 0; r < 12; ++r) {
#pragma unroll
                    for (int xx = 0; xx < 4; ++xx) {
                        const int m = xx + 12 - r;   // window idx, 1..15
                        acc[xx][r] = __hfma2(lv.h[xx], rw[m >> 2].h[m & 3], acc[xx][r]);
                    }
                }
            }
        }
        __syncthreads();   // chunk-k reads complete

        // 3) commit prefetched chunk k+1
        if (pf && act) {
#pragma unroll
            for (int q = 0; q < 8; ++q) {
                union { float4 v; __half2 h[4]; } wbuf;
                wbuf.h[0] = __floats2half2_rn(f0[q].x, f1[q].x);
                wbuf.h[1] = __floats2half2_rn(f0[q].y, f1[q].y);
                wbuf.h[2] = __floats2half2_rn(f0[q].z, f1[q].z);
                wbuf.h[3] = __floats2half2_rn(f0[q].w, f1[q].w);
                *(float4*)&sBuf[side][a0 + q][GUARD + 4 * u] = wbuf.v;
            }
        }
        __syncthreads();   // chunk k+1 visible
    }

    // ---- epilogue: fold half2 (lo=even c, hi=odd c), scale, coalesced store ----
    if (act) {
#pragma unroll
        for (int r = 0; r < 12; ++r) {
            const int i = 12 * wv + r;
            float4 o;
            o.x = (__low2float(acc[0][r]) + __high2float(acc[0][r])) * (1.f / 128.f);
            o.y = (__low2float(acc[1][r]) + __high2float(acc[1][r])) * (1.f / 128.f);
            o.z = (__low2float(acc[2][r]) + __high2float(acc[2][r])) * (1.f / 128.f);
            o.w = (__low2float(acc[3][r]) + __high2float(acc[3][r])) * (1.f / 128.f);
            *(float4*)&out[(((size_t)b * CV_V + i) * CV_H + y) * CV_W + 4 * u] = o;
        }
    }
}

extern "C" void kernel_launch(void* const* d_in, const int* in_sizes, int n_in,
                              void* d_out, int out_size, void* d_ws, size_t ws_size,
                              hipStream_t stream)
{
    const float* Lf = (const float*)d_in[0];
    const float* Rf = (const float*)d_in[1];
    float* o = (float*)d_out;
    dim3 grid(CV_H, CV_B);   // one block per (y, b): 1024 blocks x 256 thr
    dim3 block(256);
    hipLaunchKernelGGL(cost_volume_kernel, grid, block, 0, stream, Lf, Rf, o);
}